// Round 1
// baseline (210.819 us; speedup 1.0000x reference)
//
#include <hip/hip_runtime.h>
#include <stdint.h>

#define TNUM 2048
#define DDIM 1024
#define NEXP 8
#define KSEL 2
#define IDIM 1024
#define TWOI 2048
#define LIMITV 7.0f
#define ALPHAV 1.702f

typedef __attribute__((ext_vector_type(8))) short bf16x8;
typedef __attribute__((ext_vector_type(4))) float f32x4;

__device__ __forceinline__ unsigned short f2bf(float f) {
  unsigned u = __float_as_uint(f);
  u += 0x7FFF + ((u >> 16) & 1);   // round-to-nearest-even
  return (unsigned short)(u >> 16);
}

// ---------------- K0: fp32 -> bf16 weight conversion ----------------
__global__ __launch_bounds__(256) void k_cvt(const float* __restrict__ src,
                                             unsigned short* __restrict__ dst, int n8) {
  int i = blockIdx.x * blockDim.x + threadIdx.x;
  if (i >= n8) return;
  const float4* s = (const float4*)src;
  float4 a = s[2 * i], b = s[2 * i + 1];
  union { unsigned short us[8]; int4 v; } o;
  o.us[0] = f2bf(a.x); o.us[1] = f2bf(a.y); o.us[2] = f2bf(a.z); o.us[3] = f2bf(a.w);
  o.us[4] = f2bf(b.x); o.us[5] = f2bf(b.y); o.us[6] = f2bf(b.z); o.us[7] = f2bf(b.w);
  ((int4*)dst)[i] = o.v;
}

// ---------------- K1: RMSNorm + gate logits + top-2 ----------------
__global__ __launch_bounds__(256) void k_rms_gate(
    const float* __restrict__ x, const float* __restrict__ norm_w,
    const float* __restrict__ gate_w, const float* __restrict__ gate_b,
    unsigned short* __restrict__ hb, int* __restrict__ tidx,
    float* __restrict__ twt, int* __restrict__ meta) {
  const int t = blockIdx.x, tid = threadIdx.x;
  const int lane = tid & 63, wid = tid >> 6;
  __shared__ float red[4];
  __shared__ float sscale;

  const float4 v = ((const float4*)x)[t * 256 + tid];
  float ss = v.x * v.x + v.y * v.y + v.z * v.z + v.w * v.w;
#pragma unroll
  for (int o = 32; o; o >>= 1) ss += __shfl_down(ss, o);
  if (lane == 0) red[wid] = ss;
  __syncthreads();
  if (tid == 0) {
    float tot = red[0] + red[1] + red[2] + red[3];
    sscale = rsqrtf(tot * (1.0f / DDIM) + 1.1920929e-07f);
  }
  __syncthreads();
  const float sc = sscale;
  const float4 nw = ((const float4*)norm_w)[tid];
  float4 h;
  h.x = v.x * sc * nw.x; h.y = v.y * sc * nw.y;
  h.z = v.z * sc * nw.z; h.w = v.w * sc * nw.w;
  union { unsigned short us[4]; int2 v2; } hp;
  hp.us[0] = f2bf(h.x); hp.us[1] = f2bf(h.y); hp.us[2] = f2bf(h.z); hp.us[3] = f2bf(h.w);
  ((int2*)hb)[t * 256 + tid] = hp.v2;

  float lg[NEXP];
  for (int e = 0; e < NEXP; ++e) {
    const float4 g = ((const float4*)gate_w)[e * 256 + tid];
    float p = h.x * g.x + h.y * g.y + h.z * g.z + h.w * g.w;
#pragma unroll
    for (int o = 32; o; o >>= 1) p += __shfl_down(p, o);
    __syncthreads();
    if (lane == 0) red[wid] = p;
    __syncthreads();
    lg[e] = red[0] + red[1] + red[2] + red[3] + gate_b[e];
  }
  if (tid == 0) {
    int i0 = 0; float v0 = lg[0];
#pragma unroll
    for (int e = 1; e < NEXP; ++e) if (lg[e] > v0) { v0 = lg[e]; i0 = e; }
    int i1 = -1; float v1 = -3.4e38f;
#pragma unroll
    for (int e = 0; e < NEXP; ++e) if (e != i0 && lg[e] > v1) { v1 = lg[e]; i1 = e; }
    float e1 = __expf(v1 - v0);
    float w0 = 1.f / (1.f + e1);
    float w1 = e1 * w0;
    tidx[2 * t] = i0; tidx[2 * t + 1] = i1;
    twt[2 * t] = w0; twt[2 * t + 1] = w1;
    atomicAdd(&meta[i0], 1); atomicAdd(&meta[i1], 1);
  }
}

// ---------------- K2: exclusive scan of counts (tiny) ----------------
__global__ void k_scan(int* __restrict__ meta) {
  // meta[0..7]=counts, meta[8..16]=offs, meta[17..24]=cursor
  int acc = 0;
  for (int e = 0; e < NEXP; ++e) { meta[8 + e] = acc; meta[17 + e] = acc; acc += meta[e]; }
  meta[16] = acc;
}

// ---------------- K3: assign slots ----------------
__global__ __launch_bounds__(256) void k_assign(
    const int* __restrict__ tidx, const float* __restrict__ twt,
    int* __restrict__ meta, int* __restrict__ rows, int* __restrict__ sof) {
  int t = blockIdx.x * blockDim.x + threadIdx.x;
  if (t >= TNUM) return;
  for (int k = 0; k < KSEL; ++k) {
    int e = tidx[2 * t + k];
    int pos = atomicAdd(&meta[17 + e], 1);
    rows[pos] = t;
    sof[2 * t + k] = pos;
  }
}

// ---------------- K4: GEMM1 (gathered A) + SwiGLU ----------------
__global__ __launch_bounds__(256, 2) void k_gemm1(
    const unsigned short* __restrict__ hb, const unsigned short* __restrict__ w1b,
    const float* __restrict__ mlp1_b, const int* __restrict__ meta,
    const int* __restrict__ rows, unsigned short* __restrict__ actb) {
  const int e = blockIdx.z, rt = blockIdx.y, ct = blockIdx.x;
  const int offs = meta[8 + e];
  const int n_e = meta[9 + e] - offs;
  if (rt * 128 >= n_e) return;
  const int tid = threadIdx.x, lane = tid & 63, wid = tid >> 6;
  __shared__ unsigned short As[128][64];
  __shared__ unsigned short Bs[128][64];
  __shared__ int srow[128];
  if (tid < 128) {
    int r = rt * 128 + tid;
    srow[tid] = rows[offs + min(r, n_e - 1)];
  }
  __syncthreads();

  int tok[4];
#pragma unroll
  for (int i = 0; i < 4; ++i) tok[i] = srow[i * 32 + (tid >> 3)];
  const int cchunk = tid & 7;
  const unsigned short* w1e = w1b + (size_t)e * TWOI * DDIM;

  f32x4 acc[4][4];
#pragma unroll
  for (int m = 0; m < 4; ++m)
#pragma unroll
    for (int n = 0; n < 4; ++n) acc[m][n] = (f32x4){0.f, 0.f, 0.f, 0.f};

  const int wr = wid >> 1, wc = wid & 1;
  const int lrow = lane & 15, ksub = (lane >> 4) * 8;

  for (int kt = 0; kt < DDIM / 64; ++kt) {
#pragma unroll
    for (int i = 0; i < 4; ++i) {
      int r = i * 32 + (tid >> 3);
      int4 av = *(const int4*)(hb + (size_t)tok[i] * DDIM + kt * 64 + cchunk * 8);
      ((int4*)As)[r * 8 + (cchunk ^ (r & 7))] = av;
      int4 bv = *(const int4*)(w1e + (size_t)(ct * 128 + r) * DDIM + kt * 64 + cchunk * 8);
      ((int4*)Bs)[r * 8 + (cchunk ^ (r & 7))] = bv;
    }
    __syncthreads();
#pragma unroll
    for (int kk = 0; kk < 2; ++kk) {
      bf16x8 af[4], bfr[4];
#pragma unroll
      for (int m = 0; m < 4; ++m) {
        int row = wr * 64 + m * 16 + lrow;
        int chunk = ((kk * 32 + ksub) >> 3) ^ (row & 7);
        af[m] = *(const bf16x8*)&As[row][chunk * 8];
      }
#pragma unroll
      for (int n = 0; n < 4; ++n) {
        int row = wc * 64 + n * 16 + lrow;
        int chunk = ((kk * 32 + ksub) >> 3) ^ (row & 7);
        bfr[n] = *(const bf16x8*)&Bs[row][chunk * 8];
      }
#pragma unroll
      for (int m = 0; m < 4; ++m)
#pragma unroll
        for (int n = 0; n < 4; ++n)
          acc[m][n] = __builtin_amdgcn_mfma_f32_16x16x32_bf16(af[m], bfr[n], acc[m][n], 0, 0, 0);
    }
    __syncthreads();
  }

  const float* b1e = mlp1_b + e * TWOI;
#pragma unroll
  for (int m = 0; m < 4; ++m) {
#pragma unroll
    for (int n = 0; n < 4; ++n) {
      int cg = ct * 128 + wc * 64 + n * 16 + (lane & 15);
      float bias = b1e[cg];
#pragma unroll
      for (int j = 0; j < 4; ++j) {
        float val = acc[m][n][j] + bias;
        float part = __shfl_xor(val, 1);
        int rloc = wr * 64 + m * 16 + ((lane >> 4) << 2) + j;
        if (!(lane & 1)) {
          float glu = fminf(val, LIMITV);
          float lin = fminf(fmaxf(part, -LIMITV), LIMITV);
          float s = 1.f / (1.f + __expf(-ALPHAV * glu));
          float a = glu * s * (lin + 1.f);
          if (rt * 128 + rloc < n_e)
            actb[(size_t)(offs + rt * 128 + rloc) * IDIM + (cg >> 1)] = f2bf(a);
        }
      }
    }
  }
}

// ---------------- K5: GEMM2 (contiguous A) -> ybuf ----------------
__global__ __launch_bounds__(256, 2) void k_gemm2(
    const unsigned short* __restrict__ actb, const unsigned short* __restrict__ w2b,
    const float* __restrict__ mlp2_b, const int* __restrict__ meta,
    float* __restrict__ ybuf) {
  const int e = blockIdx.z, rt = blockIdx.y, ct = blockIdx.x;
  const int offs = meta[8 + e];
  const int n_e = meta[9 + e] - offs;
  if (rt * 128 >= n_e) return;
  const int tid = threadIdx.x, lane = tid & 63, wid = tid >> 6;
  __shared__ unsigned short As[128][64];
  __shared__ unsigned short Bs[128][64];

  int arow[4];
#pragma unroll
  for (int i = 0; i < 4; ++i)
    arow[i] = offs + min(rt * 128 + i * 32 + (tid >> 3), n_e - 1);
  const int cchunk = tid & 7;
  const unsigned short* w2e = w2b + (size_t)e * DDIM * IDIM;

  f32x4 acc[4][4];
#pragma unroll
  for (int m = 0; m < 4; ++m)
#pragma unroll
    for (int n = 0; n < 4; ++n) acc[m][n] = (f32x4){0.f, 0.f, 0.f, 0.f};

  const int wr = wid >> 1, wc = wid & 1;
  const int lrow = lane & 15, ksub = (lane >> 4) * 8;

  for (int kt = 0; kt < IDIM / 64; ++kt) {
#pragma unroll
    for (int i = 0; i < 4; ++i) {
      int r = i * 32 + (tid >> 3);
      int4 av = *(const int4*)(actb + (size_t)arow[i] * IDIM + kt * 64 + cchunk * 8);
      ((int4*)As)[r * 8 + (cchunk ^ (r & 7))] = av;
      int4 bv = *(const int4*)(w2e + (size_t)(ct * 128 + r) * IDIM + kt * 64 + cchunk * 8);
      ((int4*)Bs)[r * 8 + (cchunk ^ (r & 7))] = bv;
    }
    __syncthreads();
#pragma unroll
    for (int kk = 0; kk < 2; ++kk) {
      bf16x8 af[4], bfr[4];
#pragma unroll
      for (int m = 0; m < 4; ++m) {
        int row = wr * 64 + m * 16 + lrow;
        int chunk = ((kk * 32 + ksub) >> 3) ^ (row & 7);
        af[m] = *(const bf16x8*)&As[row][chunk * 8];
      }
#pragma unroll
      for (int n = 0; n < 4; ++n) {
        int row = wc * 64 + n * 16 + lrow;
        int chunk = ((kk * 32 + ksub) >> 3) ^ (row & 7);
        bfr[n] = *(const bf16x8*)&Bs[row][chunk * 8];
      }
#pragma unroll
      for (int m = 0; m < 4; ++m)
#pragma unroll
        for (int n = 0; n < 4; ++n)
          acc[m][n] = __builtin_amdgcn_mfma_f32_16x16x32_bf16(af[m], bfr[n], acc[m][n], 0, 0, 0);
    }
    __syncthreads();
  }

  const float* b2e = mlp2_b + e * DDIM;
#pragma unroll
  for (int m = 0; m < 4; ++m) {
#pragma unroll
    for (int n = 0; n < 4; ++n) {
      int d = ct * 128 + wc * 64 + n * 16 + (lane & 15);
      float bias = b2e[d];
#pragma unroll
      for (int j = 0; j < 4; ++j) {
        int rloc = wr * 64 + m * 16 + ((lane >> 4) << 2) + j;
        if (rt * 128 + rloc < n_e)
          ybuf[(size_t)(offs + rt * 128 + rloc) * DDIM + d] = acc[m][n][j] + bias;
      }
    }
  }
}

// ---------------- K6: combine (deterministic, no atomics) ----------------
__global__ __launch_bounds__(256) void k_combine(
    const float* __restrict__ x, const float* __restrict__ ybuf,
    const int* __restrict__ sof, const float* __restrict__ twt,
    float* __restrict__ out) {
  int t = blockIdx.x, tid = threadIdx.x;
  int s0 = sof[2 * t], s1 = sof[2 * t + 1];
  float w0 = twt[2 * t], w1 = twt[2 * t + 1];
  float4 xv = ((const float4*)x)[t * 256 + tid];
  float4 y0 = ((const float4*)ybuf)[(size_t)s0 * 256 + tid];
  float4 y1 = ((const float4*)ybuf)[(size_t)s1 * 256 + tid];
  float4 o;
  o.x = xv.x + w0 * y0.x + w1 * y1.x;
  o.y = xv.y + w0 * y0.y + w1 * y1.y;
  o.z = xv.z + w0 * y0.z + w1 * y1.z;
  o.w = xv.w + w0 * y0.w + w1 * y1.w;
  ((float4*)out)[t * 256 + tid] = o;
}

extern "C" void kernel_launch(void* const* d_in, const int* in_sizes, int n_in,
                              void* d_out, int out_size, void* d_ws, size_t ws_size,
                              hipStream_t stream) {
  const float* x      = (const float*)d_in[0];
  const float* norm_w = (const float*)d_in[1];
  const float* gate_w = (const float*)d_in[2];
  const float* gate_b = (const float*)d_in[3];
  const float* mlp1_w = (const float*)d_in[4];
  const float* mlp1_b = (const float*)d_in[5];
  const float* mlp2_w = (const float*)d_in[6];
  const float* mlp2_b = (const float*)d_in[7];
  float* out = (float*)d_out;

  char* w = (char*)d_ws;
  unsigned short* w1b = (unsigned short*)w; w += (size_t)NEXP * TWOI * DDIM * 2;
  unsigned short* w2b = (unsigned short*)w; w += (size_t)NEXP * DDIM * IDIM * 2;
  unsigned short* hb  = (unsigned short*)w; w += (size_t)TNUM * DDIM * 2;
  unsigned short* actb = (unsigned short*)w; w += (size_t)TNUM * KSEL * IDIM * 2;
  float* ybuf = (float*)w; w += (size_t)TNUM * KSEL * DDIM * 4;
  int*   tidx = (int*)w;  w += TNUM * KSEL * 4;
  float* twt  = (float*)w; w += TNUM * KSEL * 4;
  int*   sof  = (int*)w;  w += TNUM * KSEL * 4;
  int*   rows = (int*)w;  w += TNUM * KSEL * 4;
  int*   meta = (int*)w;  w += 32 * 4;

  hipMemsetAsync(meta, 0, 32 * 4, stream);
  k_cvt<<<(NEXP * TWOI * DDIM / 8 + 255) / 256, 256, 0, stream>>>(mlp1_w, w1b, NEXP * TWOI * DDIM / 8);
  k_cvt<<<(NEXP * DDIM * IDIM / 8 + 255) / 256, 256, 0, stream>>>(mlp2_w, w2b, NEXP * DDIM * IDIM / 8);
  k_rms_gate<<<TNUM, 256, 0, stream>>>(x, norm_w, gate_w, gate_b, hb, tidx, twt, meta);
  k_scan<<<1, 1, 0, stream>>>(meta);
  k_assign<<<(TNUM + 255) / 256, 256, 0, stream>>>(tidx, twt, meta, rows, sof);
  k_gemm1<<<dim3(TWOI / 128, TNUM / 128, NEXP), 256, 0, stream>>>(hb, w1b, mlp1_b, meta, rows, actb);
  k_gemm2<<<dim3(DDIM / 128, TNUM / 128, NEXP), 256, 0, stream>>>(actb, w2b, mlp2_b, meta, ybuf);
  k_combine<<<TNUM, 256, 0, stream>>>(x, ybuf, sof, twt, out);
}

// Round 2
// 194.919 us; speedup vs baseline: 1.0816x; 1.0816x over previous
//
#include <hip/hip_runtime.h>
#include <stdint.h>

#define TNUM 2048
#define DDIM 1024
#define NEXP 8
#define KSEL 2
#define IDIM 1024
#define TWOI 2048
#define LIMITV 7.0f
#define ALPHAV 1.702f
#define ROWT_MAX 40   // sum_e ceil(n_e/128) <= 32 + 7

typedef __attribute__((ext_vector_type(8))) short bf16x8;
typedef __attribute__((ext_vector_type(4))) float f32x4;

__device__ __forceinline__ unsigned short f2bf(float f) {
  unsigned u = __float_as_uint(f);
  u += 0x7FFF + ((u >> 16) & 1);   // round-to-nearest-even
  return (unsigned short)(u >> 16);
}

__device__ __forceinline__ int4 cvt8(float4 a, float4 b) {
  union { unsigned short us[8]; int4 v; } o;
  o.us[0] = f2bf(a.x); o.us[1] = f2bf(a.y); o.us[2] = f2bf(a.z); o.us[3] = f2bf(a.w);
  o.us[4] = f2bf(b.x); o.us[5] = f2bf(b.y); o.us[6] = f2bf(b.z); o.us[7] = f2bf(b.w);
  return o.v;
}

// ---------------- K1: RMSNorm + gate logits + top-2 ----------------
__global__ __launch_bounds__(256) void k_rms_gate(
    const float* __restrict__ x, const float* __restrict__ norm_w,
    const float* __restrict__ gate_w, const float* __restrict__ gate_b,
    unsigned short* __restrict__ hb, int* __restrict__ tidx,
    float* __restrict__ twt, int* __restrict__ meta) {
  const int t = blockIdx.x, tid = threadIdx.x;
  const int lane = tid & 63, wid = tid >> 6;
  __shared__ float red[4];
  __shared__ float sscale;

  const float4 v = ((const float4*)x)[t * 256 + tid];
  float ss = v.x * v.x + v.y * v.y + v.z * v.z + v.w * v.w;
#pragma unroll
  for (int o = 32; o; o >>= 1) ss += __shfl_down(ss, o);
  if (lane == 0) red[wid] = ss;
  __syncthreads();
  if (tid == 0) {
    float tot = red[0] + red[1] + red[2] + red[3];
    sscale = rsqrtf(tot * (1.0f / DDIM) + 1.1920929e-07f);
  }
  __syncthreads();
  const float sc = sscale;
  const float4 nw = ((const float4*)norm_w)[tid];
  float4 h;
  h.x = v.x * sc * nw.x; h.y = v.y * sc * nw.y;
  h.z = v.z * sc * nw.z; h.w = v.w * sc * nw.w;
  union { unsigned short us[4]; int2 v2; } hp;
  hp.us[0] = f2bf(h.x); hp.us[1] = f2bf(h.y); hp.us[2] = f2bf(h.z); hp.us[3] = f2bf(h.w);
  ((int2*)hb)[t * 256 + tid] = hp.v2;

  float lg[NEXP];
  for (int e = 0; e < NEXP; ++e) {
    const float4 g = ((const float4*)gate_w)[e * 256 + tid];
    float p = h.x * g.x + h.y * g.y + h.z * g.z + h.w * g.w;
#pragma unroll
    for (int o = 32; o; o >>= 1) p += __shfl_down(p, o);
    __syncthreads();
    if (lane == 0) red[wid] = p;
    __syncthreads();
    lg[e] = red[0] + red[1] + red[2] + red[3] + gate_b[e];
  }
  if (tid == 0) {
    int i0 = 0; float v0 = lg[0];
#pragma unroll
    for (int e = 1; e < NEXP; ++e) if (lg[e] > v0) { v0 = lg[e]; i0 = e; }
    int i1 = -1; float v1 = -3.4e38f;
#pragma unroll
    for (int e = 0; e < NEXP; ++e) if (e != i0 && lg[e] > v1) { v1 = lg[e]; i1 = e; }
    float e1 = __expf(v1 - v0);
    float w0 = 1.f / (1.f + e1);
    float w1 = e1 * w0;
    tidx[2 * t] = i0; tidx[2 * t + 1] = i1;
    twt[2 * t] = w0; twt[2 * t + 1] = w1;
    atomicAdd(&meta[i0], 1); atomicAdd(&meta[i1], 1);
  }
}

// ---------------- K2: scan + compact tile table ----------------
__global__ void k_scan(int* __restrict__ meta, int* __restrict__ tl) {
  // meta[0..7]=counts, meta[8..16]=offs, meta[17..24]=cursor, meta[25]=ntiles
  int acc = 0, nt = 0;
  for (int e = 0; e < NEXP; ++e) {
    meta[8 + e] = acc; meta[17 + e] = acc;
    int c = meta[e]; acc += c;
    int ntile = (c + 127) >> 7;
    for (int r = 0; r < ntile; ++r) tl[nt++] = (e << 8) | r;
  }
  meta[16] = acc;
  meta[25] = nt;
}

// ---------------- K3: assign slots ----------------
__global__ __launch_bounds__(256) void k_assign(
    const int* __restrict__ tidx, int* __restrict__ meta,
    int* __restrict__ rows, int* __restrict__ sof) {
  int t = blockIdx.x * blockDim.x + threadIdx.x;
  if (t >= TNUM) return;
  for (int k = 0; k < KSEL; ++k) {
    int e = tidx[2 * t + k];
    int pos = atomicAdd(&meta[17 + e], 1);
    rows[pos] = t;
    sof[2 * t + k] = pos;
  }
}

// ---------------- K4: GEMM1 (gathered A, fp32 B converted in-flight) + SwiGLU ----
__global__ __launch_bounds__(256, 2) void k_gemm1(
    const unsigned short* __restrict__ hb, const float* __restrict__ mlp1_w,
    const float* __restrict__ mlp1_b, const int* __restrict__ meta,
    const int* __restrict__ tl, const int* __restrict__ rows,
    unsigned short* __restrict__ actb) {
  if ((int)blockIdx.x >= meta[25]) return;
  const int tile = tl[blockIdx.x];
  const int e = tile >> 8, rt = tile & 255, ct = blockIdx.y;
  const int offs = meta[8 + e];
  const int n_e = meta[9 + e] - offs;
  const int tid = threadIdx.x, lane = tid & 63, wid = tid >> 6;

  __shared__ unsigned short As[2][128][64];
  __shared__ unsigned short Bs[2][128][64];
  __shared__ int srow[128];
  if (tid < 128) srow[tid] = rows[offs + min(rt * 128 + tid, n_e - 1)];
  __syncthreads();

  const int rbase = tid >> 3, cchunk = tid & 7;
  int tok[4];
#pragma unroll
  for (int i = 0; i < 4; ++i) tok[i] = srow[i * 32 + rbase];
  const float* w1e = mlp1_w + (size_t)e * TWOI * DDIM;

  f32x4 acc[4][4];
#pragma unroll
  for (int m = 0; m < 4; ++m)
#pragma unroll
    for (int n = 0; n < 4; ++n) acc[m][n] = (f32x4){0.f, 0.f, 0.f, 0.f};

  const int wr = wid >> 1, wc = wid & 1;
  const int lrow = lane & 15, ksub = (lane >> 4) * 8;
  const int NK = DDIM / 64;

  int4 aR[4]; float4 bLo[4], bHi[4];
#define G1_LOAD(KT)                                                             \
  _Pragma("unroll") for (int i = 0; i < 4; ++i) {                               \
    int r = i * 32 + rbase;                                                     \
    aR[i] = *(const int4*)(hb + (size_t)tok[i] * DDIM + (KT) * 64 + cchunk * 8);\
    const float4* bp = (const float4*)(w1e + (size_t)(ct * 128 + r) * DDIM +    \
                                       (KT) * 64 + cchunk * 8);                 \
    bLo[i] = bp[0]; bHi[i] = bp[1];                                             \
  }
#define G1_WRITE(BUF)                                                           \
  _Pragma("unroll") for (int i = 0; i < 4; ++i) {                               \
    int r = i * 32 + rbase;                                                     \
    ((int4*)As[BUF])[r * 8 + (cchunk ^ (r & 7))] = aR[i];                       \
    ((int4*)Bs[BUF])[r * 8 + (cchunk ^ (r & 7))] = cvt8(bLo[i], bHi[i]);        \
  }

  G1_LOAD(0)
  G1_WRITE(0)
  __syncthreads();

  int cur = 0;
  for (int kt = 0; kt < NK; ++kt) {
    const bool pf = (kt + 1 < NK);
    if (pf) { G1_LOAD(kt + 1) }
#pragma unroll
    for (int kk = 0; kk < 2; ++kk) {
      bf16x8 af[4], bfr[4];
#pragma unroll
      for (int m = 0; m < 4; ++m) {
        int row = wr * 64 + m * 16 + lrow;
        int chunk = ((kk * 32 + ksub) >> 3) ^ (row & 7);
        af[m] = *(const bf16x8*)&As[cur][row][chunk * 8];
      }
#pragma unroll
      for (int n = 0; n < 4; ++n) {
        int row = wc * 64 + n * 16 + lrow;
        int chunk = ((kk * 32 + ksub) >> 3) ^ (row & 7);
        bfr[n] = *(const bf16x8*)&Bs[cur][row][chunk * 8];
      }
#pragma unroll
      for (int m = 0; m < 4; ++m)
#pragma unroll
        for (int n = 0; n < 4; ++n)
          acc[m][n] = __builtin_amdgcn_mfma_f32_16x16x32_bf16(af[m], bfr[n], acc[m][n], 0, 0, 0);
    }
    if (pf) { G1_WRITE(cur ^ 1) }
    __syncthreads();
    cur ^= 1;
  }
#undef G1_LOAD
#undef G1_WRITE

  const float* b1e = mlp1_b + e * TWOI;
#pragma unroll
  for (int m = 0; m < 4; ++m) {
#pragma unroll
    for (int n = 0; n < 4; ++n) {
      int cg = ct * 128 + wc * 64 + n * 16 + (lane & 15);
      float bias = b1e[cg];
#pragma unroll
      for (int j = 0; j < 4; ++j) {
        float val = acc[m][n][j] + bias;
        float part = __shfl_xor(val, 1);
        int rloc = wr * 64 + m * 16 + ((lane >> 4) << 2) + j;
        if (!(lane & 1)) {
          float glu = fminf(val, LIMITV);
          float lin = fminf(fmaxf(part, -LIMITV), LIMITV);
          float s = 1.f / (1.f + __expf(-ALPHAV * glu));
          float a = glu * s * (lin + 1.f);
          if (rt * 128 + rloc < n_e)
            actb[(size_t)(offs + rt * 128 + rloc) * IDIM + (cg >> 1)] = f2bf(a);
        }
      }
    }
  }
}

// ---------------- K5: GEMM2 (contiguous A, fp32 B converted in-flight) ----------
__global__ __launch_bounds__(256, 2) void k_gemm2(
    const unsigned short* __restrict__ actb, const float* __restrict__ mlp2_w,
    const float* __restrict__ mlp2_b, const int* __restrict__ meta,
    const int* __restrict__ tl, float* __restrict__ ybuf) {
  if ((int)blockIdx.x >= meta[25]) return;
  const int tile = tl[blockIdx.x];
  const int e = tile >> 8, rt = tile & 255, ct = blockIdx.y;
  const int offs = meta[8 + e];
  const int n_e = meta[9 + e] - offs;
  const int tid = threadIdx.x, lane = tid & 63, wid = tid >> 6;

  __shared__ unsigned short As[2][128][64];
  __shared__ unsigned short Bs[2][128][64];

  const int rbase = tid >> 3, cchunk = tid & 7;
  int arow[4];
#pragma unroll
  for (int i = 0; i < 4; ++i)
    arow[i] = offs + min(rt * 128 + i * 32 + rbase, n_e - 1);
  const float* w2e = mlp2_w + (size_t)e * DDIM * IDIM;

  f32x4 acc[4][4];
#pragma unroll
  for (int m = 0; m < 4; ++m)
#pragma unroll
    for (int n = 0; n < 4; ++n) acc[m][n] = (f32x4){0.f, 0.f, 0.f, 0.f};

  const int wr = wid >> 1, wc = wid & 1;
  const int lrow = lane & 15, ksub = (lane >> 4) * 8;
  const int NK = IDIM / 64;

  int4 aR[4]; float4 bLo[4], bHi[4];
#define G2_LOAD(KT)                                                               \
  _Pragma("unroll") for (int i = 0; i < 4; ++i) {                                 \
    int r = i * 32 + rbase;                                                       \
    aR[i] = *(const int4*)(actb + (size_t)arow[i] * IDIM + (KT) * 64 + cchunk * 8);\
    const float4* bp = (const float4*)(w2e + (size_t)(ct * 128 + r) * IDIM +      \
                                       (KT) * 64 + cchunk * 8);                   \
    bLo[i] = bp[0]; bHi[i] = bp[1];                                               \
  }
#define G2_WRITE(BUF)                                                             \
  _Pragma("unroll") for (int i = 0; i < 4; ++i) {                                 \
    int r = i * 32 + rbase;                                                       \
    ((int4*)As[BUF])[r * 8 + (cchunk ^ (r & 7))] = aR[i];                         \
    ((int4*)Bs[BUF])[r * 8 + (cchunk ^ (r & 7))] = cvt8(bLo[i], bHi[i]);          \
  }

  G2_LOAD(0)
  G2_WRITE(0)
  __syncthreads();

  int cur = 0;
  for (int kt = 0; kt < NK; ++kt) {
    const bool pf = (kt + 1 < NK);
    if (pf) { G2_LOAD(kt + 1) }
#pragma unroll
    for (int kk = 0; kk < 2; ++kk) {
      bf16x8 af[4], bfr[4];
#pragma unroll
      for (int m = 0; m < 4; ++m) {
        int row = wr * 64 + m * 16 + lrow;
        int chunk = ((kk * 32 + ksub) >> 3) ^ (row & 7);
        af[m] = *(const bf16x8*)&As[cur][row][chunk * 8];
      }
#pragma unroll
      for (int n = 0; n < 4; ++n) {
        int row = wc * 64 + n * 16 + lrow;
        int chunk = ((kk * 32 + ksub) >> 3) ^ (row & 7);
        bfr[n] = *(const bf16x8*)&Bs[cur][row][chunk * 8];
      }
#pragma unroll
      for (int m = 0; m < 4; ++m)
#pragma unroll
        for (int n = 0; n < 4; ++n)
          acc[m][n] = __builtin_amdgcn_mfma_f32_16x16x32_bf16(af[m], bfr[n], acc[m][n], 0, 0, 0);
    }
    if (pf) { G2_WRITE(cur ^ 1) }
    __syncthreads();
    cur ^= 1;
  }
#undef G2_LOAD
#undef G2_WRITE

  const float* b2e = mlp2_b + e * DDIM;
#pragma unroll
  for (int m = 0; m < 4; ++m) {
#pragma unroll
    for (int n = 0; n < 4; ++n) {
      int d = ct * 128 + wc * 64 + n * 16 + (lane & 15);
      float bias = b2e[d];
#pragma unroll
      for (int j = 0; j < 4; ++j) {
        int rloc = wr * 64 + m * 16 + ((lane >> 4) << 2) + j;
        if (rt * 128 + rloc < n_e)
          ybuf[(size_t)(offs + rt * 128 + rloc) * DDIM + d] = acc[m][n][j] + bias;
      }
    }
  }
}

// ---------------- K6: combine (deterministic, no atomics) ----------------
__global__ __launch_bounds__(256) void k_combine(
    const float* __restrict__ x, const float* __restrict__ ybuf,
    const int* __restrict__ sof, const float* __restrict__ twt,
    float* __restrict__ out) {
  int t = blockIdx.x, tid = threadIdx.x;
  int s0 = sof[2 * t], s1 = sof[2 * t + 1];
  float w0 = twt[2 * t], w1 = twt[2 * t + 1];
  float4 xv = ((const float4*)x)[t * 256 + tid];
  float4 y0 = ((const float4*)ybuf)[(size_t)s0 * 256 + tid];
  float4 y1 = ((const float4*)ybuf)[(size_t)s1 * 256 + tid];
  float4 o;
  o.x = xv.x + w0 * y0.x + w1 * y1.x;
  o.y = xv.y + w0 * y0.y + w1 * y1.y;
  o.z = xv.z + w0 * y0.z + w1 * y1.z;
  o.w = xv.w + w0 * y0.w + w1 * y1.w;
  ((float4*)out)[t * 256 + tid] = o;
}

extern "C" void kernel_launch(void* const* d_in, const int* in_sizes, int n_in,
                              void* d_out, int out_size, void* d_ws, size_t ws_size,
                              hipStream_t stream) {
  const float* x      = (const float*)d_in[0];
  const float* norm_w = (const float*)d_in[1];
  const float* gate_w = (const float*)d_in[2];
  const float* gate_b = (const float*)d_in[3];
  const float* mlp1_w = (const float*)d_in[4];
  const float* mlp1_b = (const float*)d_in[5];
  const float* mlp2_w = (const float*)d_in[6];
  const float* mlp2_b = (const float*)d_in[7];
  float* out = (float*)d_out;

  char* w = (char*)d_ws;
  unsigned short* hb  = (unsigned short*)w; w += (size_t)TNUM * DDIM * 2;
  unsigned short* actb = (unsigned short*)w; w += (size_t)TNUM * KSEL * IDIM * 2;
  float* ybuf = (float*)w; w += (size_t)TNUM * KSEL * DDIM * 4;
  int*   tidx = (int*)w;  w += TNUM * KSEL * 4;
  float* twt  = (float*)w; w += TNUM * KSEL * 4;
  int*   sof  = (int*)w;  w += TNUM * KSEL * 4;
  int*   rows = (int*)w;  w += TNUM * KSEL * 4;
  int*   meta = (int*)w;  w += 32 * 4;
  int*   tl   = (int*)w;  w += 64 * 4;

  hipMemsetAsync(meta, 0, 32 * 4, stream);
  k_rms_gate<<<TNUM, 256, 0, stream>>>(x, norm_w, gate_w, gate_b, hb, tidx, twt, meta);
  k_scan<<<1, 1, 0, stream>>>(meta, tl);
  k_assign<<<(TNUM + 255) / 256, 256, 0, stream>>>(tidx, meta, rows, sof);
  k_gemm1<<<dim3(ROWT_MAX, TWOI / 128), 256, 0, stream>>>(hb, mlp1_w, mlp1_b, meta, tl, rows, actb);
  k_gemm2<<<dim3(ROWT_MAX, DDIM / 128), 256, 0, stream>>>(actb, mlp2_w, mlp2_b, meta, tl, ybuf);
  k_combine<<<TNUM, 256, 0, stream>>>(x, ybuf, sof, twt, out);
}

// Round 3
// 170.243 us; speedup vs baseline: 1.2383x; 1.1449x over previous
//
#include <hip/hip_runtime.h>
#include <stdint.h>

#define TNUM 2048
#define DDIM 1024
#define NEXP 8
#define KSEL 2
#define IDIM 1024
#define TWOI 2048
#define LIMITV 7.0f
#define ALPHAV 1.702f
#define ROWT_MAX 40   // sum_e ceil(n_e/128) <= 32 + 7

typedef __attribute__((ext_vector_type(8))) short bf16x8;
typedef __attribute__((ext_vector_type(4))) float f32x4;

__device__ __forceinline__ unsigned short f2bf(float f) {
  unsigned u = __float_as_uint(f);
  u += 0x7FFF + ((u >> 16) & 1);   // round-to-nearest-even
  return (unsigned short)(u >> 16);
}

__device__ __forceinline__ int4 cvt8(float4 a, float4 b) {
  union { unsigned short us[8]; int4 v; } o;
  o.us[0] = f2bf(a.x); o.us[1] = f2bf(a.y); o.us[2] = f2bf(a.z); o.us[3] = f2bf(a.w);
  o.us[4] = f2bf(b.x); o.us[5] = f2bf(b.y); o.us[6] = f2bf(b.z); o.us[7] = f2bf(b.w);
  return o.v;
}

// Bijective chunked XCD swizzle (m204): round-robin bid -> contiguous job chunk per XCD.
__device__ __forceinline__ int xcd_swz(int bid, int total) {
  int q = total >> 3, r = total & 7;
  int xcd = bid & 7, pos = bid >> 3;
  return (xcd < r ? xcd * (q + 1) : r * (q + 1) + (xcd - r) * q) + pos;
}

// ---------------- K1: RMSNorm + gate logits + top-2 ----------------
__global__ __launch_bounds__(256) void k_rms_gate(
    const float* __restrict__ x, const float* __restrict__ norm_w,
    const float* __restrict__ gate_w, const float* __restrict__ gate_b,
    unsigned short* __restrict__ hb, int* __restrict__ tidx,
    float* __restrict__ twt, int* __restrict__ meta) {
  const int t = blockIdx.x, tid = threadIdx.x;
  const int lane = tid & 63, wid = tid >> 6;
  __shared__ float red[4];
  __shared__ float pred[4][NEXP];
  __shared__ float sscale;

  const float4 v = ((const float4*)x)[t * 256 + tid];
  float ss = v.x * v.x + v.y * v.y + v.z * v.z + v.w * v.w;
#pragma unroll
  for (int o = 32; o; o >>= 1) ss += __shfl_down(ss, o);
  if (lane == 0) red[wid] = ss;
  __syncthreads();
  if (tid == 0) {
    float tot = red[0] + red[1] + red[2] + red[3];
    sscale = rsqrtf(tot * (1.0f / DDIM) + 1.1920929e-07f);
  }
  __syncthreads();
  const float sc = sscale;
  const float4 nw = ((const float4*)norm_w)[tid];
  float4 h;
  h.x = v.x * sc * nw.x; h.y = v.y * sc * nw.y;
  h.z = v.z * sc * nw.z; h.w = v.w * sc * nw.w;
  union { unsigned short us[4]; int2 v2; } hp;
  hp.us[0] = f2bf(h.x); hp.us[1] = f2bf(h.y); hp.us[2] = f2bf(h.z); hp.us[3] = f2bf(h.w);
  ((int2*)hb)[t * 256 + tid] = hp.v2;

  float p[NEXP];
#pragma unroll
  for (int e = 0; e < NEXP; ++e) {
    const float4 g = ((const float4*)gate_w)[e * 256 + tid];
    p[e] = h.x * g.x + h.y * g.y + h.z * g.z + h.w * g.w;
  }
#pragma unroll
  for (int e = 0; e < NEXP; ++e) {
#pragma unroll
    for (int o = 32; o; o >>= 1) p[e] += __shfl_down(p[e], o);
  }
  if (lane == 0) {
#pragma unroll
    for (int e = 0; e < NEXP; ++e) pred[wid][e] = p[e];
  }
  __syncthreads();
  if (tid == 0) {
    float lg[NEXP];
#pragma unroll
    for (int e = 0; e < NEXP; ++e)
      lg[e] = pred[0][e] + pred[1][e] + pred[2][e] + pred[3][e] + gate_b[e];
    int i0 = 0; float v0 = lg[0];
#pragma unroll
    for (int e = 1; e < NEXP; ++e) if (lg[e] > v0) { v0 = lg[e]; i0 = e; }
    int i1 = -1; float v1 = -3.4e38f;
#pragma unroll
    for (int e = 0; e < NEXP; ++e) if (e != i0 && lg[e] > v1) { v1 = lg[e]; i1 = e; }
    float e1 = __expf(v1 - v0);
    float w0 = 1.f / (1.f + e1);
    float w1 = e1 * w0;
    tidx[2 * t] = i0; tidx[2 * t + 1] = i1;
    twt[2 * t] = w0; twt[2 * t + 1] = w1;
    atomicAdd(&meta[i0], 1); atomicAdd(&meta[i1], 1);
  }
}

// ---------------- K2: scan + compact tile table ----------------
__global__ void k_scan(int* __restrict__ meta, int* __restrict__ tl) {
  // meta[0..7]=counts, meta[8..16]=offs, meta[17..24]=cursor, meta[25]=ntiles
  int acc = 0, nt = 0;
  for (int e = 0; e < NEXP; ++e) {
    meta[8 + e] = acc; meta[17 + e] = acc;
    int c = meta[e]; acc += c;
    int ntile = (c + 127) >> 7;
    for (int r = 0; r < ntile; ++r) tl[nt++] = (e << 8) | r;
  }
  meta[16] = acc;
  meta[25] = nt;
}

// ---------------- K3: assign slots ----------------
__global__ __launch_bounds__(256) void k_assign(
    const int* __restrict__ tidx, int* __restrict__ meta,
    int* __restrict__ rows, int* __restrict__ sof) {
  int t = blockIdx.x * blockDim.x + threadIdx.x;
  if (t >= TNUM) return;
  for (int k = 0; k < KSEL; ++k) {
    int e = tidx[2 * t + k];
    int pos = atomicAdd(&meta[17 + e], 1);
    rows[pos] = t;
    sof[2 * t + k] = pos;
  }
}

// ---------------- K4: GEMM1 (gathered A, fp32 B converted in-flight) + SwiGLU ----
__global__ __launch_bounds__(256, 2) void k_gemm1(
    const unsigned short* __restrict__ hb, const float* __restrict__ mlp1_w,
    const float* __restrict__ mlp1_b, const int* __restrict__ meta,
    const int* __restrict__ tl, const int* __restrict__ rows,
    unsigned short* __restrict__ actb) {
  const int nt = meta[25];
  const int total = nt * (TWOI / 128);
  const int bid = blockIdx.x;
  if (bid >= total) return;
  const int j = xcd_swz(bid, total);
  const int ct = j / nt;
  const int tile = tl[j - ct * nt];
  const int e = tile >> 8, rt = tile & 255;
  const int offs = meta[8 + e];
  const int n_e = meta[9 + e] - offs;
  const int tid = threadIdx.x, lane = tid & 63, wid = tid >> 6;

  __shared__ unsigned short As[2][128][64];
  __shared__ unsigned short Bs[2][128][64];
  __shared__ int srow[128];
  if (tid < 128) srow[tid] = rows[offs + min(rt * 128 + tid, n_e - 1)];
  __syncthreads();

  const int rbase = tid >> 3, cchunk = tid & 7;
  int tok[4];
#pragma unroll
  for (int i = 0; i < 4; ++i) tok[i] = srow[i * 32 + rbase];
  const float* w1e = mlp1_w + (size_t)e * TWOI * DDIM;

  f32x4 acc[4][4];
#pragma unroll
  for (int m = 0; m < 4; ++m)
#pragma unroll
    for (int n = 0; n < 4; ++n) acc[m][n] = (f32x4){0.f, 0.f, 0.f, 0.f};

  const int wr = wid >> 1, wc = wid & 1;
  const int lrow = lane & 15, ksub = (lane >> 4) * 8;
  const int NK = DDIM / 64;

  int4 aR[4]; float4 bLo[4], bHi[4];
#define G1_LOAD(KT)                                                             \
  _Pragma("unroll") for (int i = 0; i < 4; ++i) {                               \
    int r = i * 32 + rbase;                                                     \
    aR[i] = *(const int4*)(hb + (size_t)tok[i] * DDIM + (KT) * 64 + cchunk * 8);\
    const float4* bp = (const float4*)(w1e + (size_t)(ct * 128 + r) * DDIM +    \
                                       (KT) * 64 + cchunk * 8);                 \
    bLo[i] = bp[0]; bHi[i] = bp[1];                                             \
  }
#define G1_WRITE(BUF)                                                           \
  _Pragma("unroll") for (int i = 0; i < 4; ++i) {                               \
    int r = i * 32 + rbase;                                                     \
    ((int4*)As[BUF])[r * 8 + (cchunk ^ (r & 7))] = aR[i];                       \
    ((int4*)Bs[BUF])[r * 8 + (cchunk ^ (r & 7))] = cvt8(bLo[i], bHi[i]);        \
  }

  G1_LOAD(0)
  G1_WRITE(0)
  __syncthreads();

  int cur = 0;
  for (int kt = 0; kt < NK; ++kt) {
    const bool pf = (kt + 1 < NK);
    if (pf) { G1_LOAD(kt + 1) }
#pragma unroll
    for (int kk = 0; kk < 2; ++kk) {
      bf16x8 af[4], bfr[4];
#pragma unroll
      for (int m = 0; m < 4; ++m) {
        int row = wr * 64 + m * 16 + lrow;
        int chunk = ((kk * 32 + ksub) >> 3) ^ (row & 7);
        af[m] = *(const bf16x8*)&As[cur][row][chunk * 8];
      }
#pragma unroll
      for (int n = 0; n < 4; ++n) {
        int row = wc * 64 + n * 16 + lrow;
        int chunk = ((kk * 32 + ksub) >> 3) ^ (row & 7);
        bfr[n] = *(const bf16x8*)&Bs[cur][row][chunk * 8];
      }
#pragma unroll
      for (int m = 0; m < 4; ++m)
#pragma unroll
        for (int n = 0; n < 4; ++n)
          acc[m][n] = __builtin_amdgcn_mfma_f32_16x16x32_bf16(af[m], bfr[n], acc[m][n], 0, 0, 0);
    }
    if (pf) { G1_WRITE(cur ^ 1) }
    __syncthreads();
    cur ^= 1;
  }
#undef G1_LOAD
#undef G1_WRITE

  const float* b1e = mlp1_b + e * TWOI;
#pragma unroll
  for (int m = 0; m < 4; ++m) {
#pragma unroll
    for (int n = 0; n < 4; ++n) {
      int cg = ct * 128 + wc * 64 + n * 16 + (lane & 15);
      float bias = b1e[cg];
#pragma unroll
      for (int j2 = 0; j2 < 4; ++j2) {
        float val = acc[m][n][j2] + bias;
        float part = __shfl_xor(val, 1);
        int rloc = wr * 64 + m * 16 + ((lane >> 4) << 2) + j2;
        if (!(lane & 1)) {
          float glu = fminf(val, LIMITV);
          float lin = fminf(fmaxf(part, -LIMITV), LIMITV);
          float s = 1.f / (1.f + __expf(-ALPHAV * glu));
          float a = glu * s * (lin + 1.f);
          if (rt * 128 + rloc < n_e)
            actb[(size_t)(offs + rt * 128 + rloc) * IDIM + (cg >> 1)] = f2bf(a);
        }
      }
    }
  }
}

// ---------------- K5: GEMM2 (contiguous A, fp32 B converted in-flight) ----------
__global__ __launch_bounds__(256, 2) void k_gemm2(
    const unsigned short* __restrict__ actb, const float* __restrict__ mlp2_w,
    const float* __restrict__ mlp2_b, const int* __restrict__ meta,
    const int* __restrict__ tl, float* __restrict__ ybuf) {
  const int nt = meta[25];
  const int total = nt * (DDIM / 128);
  const int bid = blockIdx.x;
  if (bid >= total) return;
  const int j = xcd_swz(bid, total);
  const int ct = j / nt;
  const int tile = tl[j - ct * nt];
  const int e = tile >> 8, rt = tile & 255;
  const int offs = meta[8 + e];
  const int n_e = meta[9 + e] - offs;
  const int tid = threadIdx.x, lane = tid & 63, wid = tid >> 6;

  __shared__ unsigned short As[2][128][64];
  __shared__ unsigned short Bs[2][128][64];

  const int rbase = tid >> 3, cchunk = tid & 7;
  int arow[4];
#pragma unroll
  for (int i = 0; i < 4; ++i)
    arow[i] = offs + min(rt * 128 + i * 32 + rbase, n_e - 1);
  const float* w2e = mlp2_w + (size_t)e * DDIM * IDIM;

  f32x4 acc[4][4];
#pragma unroll
  for (int m = 0; m < 4; ++m)
#pragma unroll
    for (int n = 0; n < 4; ++n) acc[m][n] = (f32x4){0.f, 0.f, 0.f, 0.f};

  const int wr = wid >> 1, wc = wid & 1;
  const int lrow = lane & 15, ksub = (lane >> 4) * 8;
  const int NK = IDIM / 64;

  int4 aR[4]; float4 bLo[4], bHi[4];
#define G2_LOAD(KT)                                                               \
  _Pragma("unroll") for (int i = 0; i < 4; ++i) {                                 \
    int r = i * 32 + rbase;                                                       \
    aR[i] = *(const int4*)(actb + (size_t)arow[i] * IDIM + (KT) * 64 + cchunk * 8);\
    const float4* bp = (const float4*)(w2e + (size_t)(ct * 128 + r) * IDIM +      \
                                       (KT) * 64 + cchunk * 8);                   \
    bLo[i] = bp[0]; bHi[i] = bp[1];                                               \
  }
#define G2_WRITE(BUF)                                                             \
  _Pragma("unroll") for (int i = 0; i < 4; ++i) {                                 \
    int r = i * 32 + rbase;                                                       \
    ((int4*)As[BUF])[r * 8 + (cchunk ^ (r & 7))] = aR[i];                         \
    ((int4*)Bs[BUF])[r * 8 + (cchunk ^ (r & 7))] = cvt8(bLo[i], bHi[i]);          \
  }

  G2_LOAD(0)
  G2_WRITE(0)
  __syncthreads();

  int cur = 0;
  for (int kt = 0; kt < NK; ++kt) {
    const bool pf = (kt + 1 < NK);
    if (pf) { G2_LOAD(kt + 1) }
#pragma unroll
    for (int kk = 0; kk < 2; ++kk) {
      bf16x8 af[4], bfr[4];
#pragma unroll
      for (int m = 0; m < 4; ++m) {
        int row = wr * 64 + m * 16 + lrow;
        int chunk = ((kk * 32 + ksub) >> 3) ^ (row & 7);
        af[m] = *(const bf16x8*)&As[cur][row][chunk * 8];
      }
#pragma unroll
      for (int n = 0; n < 4; ++n) {
        int row = wc * 64 + n * 16 + lrow;
        int chunk = ((kk * 32 + ksub) >> 3) ^ (row & 7);
        bfr[n] = *(const bf16x8*)&Bs[cur][row][chunk * 8];
      }
#pragma unroll
      for (int m = 0; m < 4; ++m)
#pragma unroll
        for (int n = 0; n < 4; ++n)
          acc[m][n] = __builtin_amdgcn_mfma_f32_16x16x32_bf16(af[m], bfr[n], acc[m][n], 0, 0, 0);
    }
    if (pf) { G2_WRITE(cur ^ 1) }
    __syncthreads();
    cur ^= 1;
  }
#undef G2_LOAD
#undef G2_WRITE

  const float* b2e = mlp2_b + e * DDIM;
#pragma unroll
  for (int m = 0; m < 4; ++m) {
#pragma unroll
    for (int n = 0; n < 4; ++n) {
      int d = ct * 128 + wc * 64 + n * 16 + (lane & 15);
      float bias = b2e[d];
#pragma unroll
      for (int j2 = 0; j2 < 4; ++j2) {
        int rloc = wr * 64 + m * 16 + ((lane >> 4) << 2) + j2;
        if (rt * 128 + rloc < n_e)
          ybuf[(size_t)(offs + rt * 128 + rloc) * DDIM + d] = acc[m][n][j2] + bias;
      }
    }
  }
}

// ---------------- K6: combine (deterministic, no atomics) ----------------
__global__ __launch_bounds__(256) void k_combine(
    const float* __restrict__ x, const float* __restrict__ ybuf,
    const int* __restrict__ sof, const float* __restrict__ twt,
    float* __restrict__ out) {
  int t = blockIdx.x, tid = threadIdx.x;
  int s0 = sof[2 * t], s1 = sof[2 * t + 1];
  float w0 = twt[2 * t], w1 = twt[2 * t + 1];
  float4 xv = ((const float4*)x)[t * 256 + tid];
  float4 y0 = ((const float4*)ybuf)[(size_t)s0 * 256 + tid];
  float4 y1 = ((const float4*)ybuf)[(size_t)s1 * 256 + tid];
  float4 o;
  o.x = xv.x + w0 * y0.x + w1 * y1.x;
  o.y = xv.y + w0 * y0.y + w1 * y1.y;
  o.z = xv.z + w0 * y0.z + w1 * y1.z;
  o.w = xv.w + w0 * y0.w + w1 * y1.w;
  ((float4*)out)[t * 256 + tid] = o;
}

extern "C" void kernel_launch(void* const* d_in, const int* in_sizes, int n_in,
                              void* d_out, int out_size, void* d_ws, size_t ws_size,
                              hipStream_t stream) {
  const float* x      = (const float*)d_in[0];
  const float* norm_w = (const float*)d_in[1];
  const float* gate_w = (const float*)d_in[2];
  const float* gate_b = (const float*)d_in[3];
  const float* mlp1_w = (const float*)d_in[4];
  const float* mlp1_b = (const float*)d_in[5];
  const float* mlp2_w = (const float*)d_in[6];
  const float* mlp2_b = (const float*)d_in[7];
  float* out = (float*)d_out;

  char* w = (char*)d_ws;
  unsigned short* hb  = (unsigned short*)w; w += (size_t)TNUM * DDIM * 2;
  unsigned short* actb = (unsigned short*)w; w += (size_t)TNUM * KSEL * IDIM * 2;
  float* ybuf = (float*)w; w += (size_t)TNUM * KSEL * DDIM * 4;
  int*   tidx = (int*)w;  w += TNUM * KSEL * 4;
  float* twt  = (float*)w; w += TNUM * KSEL * 4;
  int*   sof  = (int*)w;  w += TNUM * KSEL * 4;
  int*   rows = (int*)w;  w += TNUM * KSEL * 4;
  int*   meta = (int*)w;  w += 32 * 4;
  int*   tl   = (int*)w;  w += 64 * 4;

  hipMemsetAsync(meta, 0, 32 * 4, stream);
  k_rms_gate<<<TNUM, 256, 0, stream>>>(x, norm_w, gate_w, gate_b, hb, tidx, twt, meta);
  k_scan<<<1, 1, 0, stream>>>(meta, tl);
  k_assign<<<(TNUM + 255) / 256, 256, 0, stream>>>(tidx, meta, rows, sof);
  k_gemm1<<<dim3(ROWT_MAX * (TWOI / 128)), 256, 0, stream>>>(hb, mlp1_w, mlp1_b, meta, tl, rows, actb);
  k_gemm2<<<dim3(ROWT_MAX * (DDIM / 128)), 256, 0, stream>>>(actb, mlp2_w, mlp2_b, meta, tl, ybuf);
  k_combine<<<TNUM, 256, 0, stream>>>(x, ybuf, sof, twt, out);
}